// Round 14
// baseline (610.230 us; speedup 1.0000x reference)
//
#include <hip/hip_runtime.h>

// ABLATION ROUND. Kernels launched in order:
//   1) prep_w      — pack [We|Ww] into Wtile bf16 (round-9 layout, d_ws)
//   2) probe_compute — COMPUTE PHASE ONLY, x10 steps: 20 ds_read_b128 +
//      48 MFMA + 1 lgkm-barrier per step from STATIC LDS. No global loads,
//      no ds_writes in-loop. Measures whether LDS-read and MFMA pipes
//      overlap at 2 waves/SIMD. Writes to d_out (overwritten by 3).
//   3) msg_kernel  — unchanged round-9 best (111.7 us), produces the output.

#define DD   768
#define NCOL 256
#define KTOT 1536
#define BM   192
#define BN   256
#define BK   64
#define NIT  24
#define PSTEPS 240   // 10x main loop steps

typedef __bf16 bf16;
typedef __attribute__((ext_vector_type(8))) __bf16 bf16x8;
typedef __attribute__((ext_vector_type(4))) float f32x4;
typedef __attribute__((ext_vector_type(4))) unsigned int u32x4;

// 128B rows. XOR row bits into 16B-slot bits (rounds 5-13).
__device__ __forceinline__ int swz(int row, int kb) {
  return row * 128 + (kb ^ (((row ^ (row >> 3)) & 7) << 4));
}

// ---- prep: Wtile chunks of 16B: i = ((T*4+mt)*3+c)*512 + t ->
//      o = mt*192 + c*64 + (t>>3), k = T*64 + (t&7)*8 ; k<768 We else Ww ----
__global__ void prep_w(const float* __restrict__ We, const float* __restrict__ Ww,
                       unsigned short* __restrict__ Wtile) {
  int i = blockIdx.x * blockDim.x + threadIdx.x;  // 147456 chunks
  int t = i & 511;
  int g = i >> 9;
  int c = g % 3;
  int h = g / 3;
  int mt = h & 3, T = h >> 2;
  int o = mt * 192 + c * 64 + (t >> 3);
  int k = T * 64 + (t & 7) * 8;
  const float* src = (k < DD) ? (We + (size_t)o * DD + k)
                              : (Ww + (size_t)o * DD + (k - DD));
  f32x4 v0 = *(const f32x4*)src;
  f32x4 v1 = *(const f32x4*)(src + 4);
  union { bf16 h8[8]; u32x4 q; } u;
  u.h8[0]=(bf16)v0[0]; u.h8[1]=(bf16)v0[1]; u.h8[2]=(bf16)v0[2]; u.h8[3]=(bf16)v0[3];
  u.h8[4]=(bf16)v1[0]; u.h8[5]=(bf16)v1[1]; u.h8[6]=(bf16)v1[2]; u.h8[7]=(bf16)v1[3];
  *(u32x4*)(Wtile + (size_t)i * 8) = u.q;
}

// ==================== PROBE: compute phase in isolation ====================
__global__ __launch_bounds__(512, 2)
void probe_compute(const unsigned short* __restrict__ Wtile,
                   const float* __restrict__ e_vw, float* __restrict__ out) {
  __shared__ __align__(16) unsigned char smem[2 * 57344];
  const int tid = threadIdx.x;
  const int p = blockIdx.x;
  const int slot = p >> 3;
  const int bb = (p & 7) * 16 + (slot >> 2);
  const int mt = slot & 3;

  // staging maps (round-9 identical), used ONCE to init both buffers
  const unsigned short* pA = Wtile + (size_t)(mt * 3) * 4096 + (size_t)tid * 8;
  const int rA = tid >> 3, kA = (tid & 7) * 16;
  int wAo[3];
  #pragma unroll
  for (int c = 0; c < 3; ++c) wAo[c] = swz(c * 64 + rA, kA);
  const int nq = tid & 63, kk = tid >> 6;
  const size_t xofs = (size_t)bb * DD * NCOL + (size_t)(kk * 8) * NCOL + nq * 4;
  const float* pE = e_vw + xofs;
  int wBo[4];
  #pragma unroll
  for (int j = 0; j < 4; ++j) wBo[j] = swz(4 * nq + j, kk * 16);

  #pragma unroll
  for (int T = 0; T < 2; ++T) {
    u32x4 aR0 = *(const u32x4*)(pA + (size_t)T * 49152);
    u32x4 aR1 = *(const u32x4*)(pA + (size_t)T * 49152 + 4096);
    u32x4 aR2 = *(const u32x4*)(pA + (size_t)T * 49152 + 8192);
    f32x4 bR[8];
    #pragma unroll
    for (int i = 0; i < 8; ++i)
      bR[i] = *(const f32x4*)(pE + (size_t)T * BK * NCOL + (size_t)i * NCOL);
    unsigned char* base = smem + T * 57344;
    *(u32x4*)(base + wAo[0]) = aR0;
    *(u32x4*)(base + wAo[1]) = aR1;
    *(u32x4*)(base + wAo[2]) = aR2;
    unsigned char* bBase = base + 24576;
    #pragma unroll
    for (int j = 0; j < 4; ++j) {
      union { bf16 h8[8]; u32x4 q; } u;
      #pragma unroll
      for (int i = 0; i < 8; ++i) u.h8[i] = (bf16)bR[i][j];
      *(u32x4*)(bBase + wBo[j]) = u.q;
    }
  }
  asm volatile("s_waitcnt lgkmcnt(0)" ::: "memory");
  __builtin_amdgcn_s_barrier();

  // compute loop: EXACT round-9 per-step instruction mix minus staging
  const int lane = tid & 63, wid = tid >> 6;
  const int wm = wid >> 2, wn = wid & 3;
  const int lr = lane & 15, qk = (lane >> 4) * 16;
  f32x4 acc[6][4] = {};

  for (int tt = 0; tt < PSTEPS; ++tt) {
    const int c = tt & 1;
    const unsigned char* bA = smem + c * 57344;
    const unsigned char* bB = bA + 24576;
    bf16x8 af0[6], bfv0[4], af1[6], bfv1[4];
    #pragma unroll
    for (int m = 0; m < 6; ++m)
      af0[m] = *(const bf16x8*)(bA + swz(wm * 96 + m * 16 + lr, qk));
    #pragma unroll
    for (int n = 0; n < 4; ++n)
      bfv0[n] = *(const bf16x8*)(bB + swz(wn * 64 + n * 16 + lr, qk));
    #pragma unroll
    for (int m = 0; m < 6; ++m)
      af1[m] = *(const bf16x8*)(bA + swz(wm * 96 + m * 16 + lr, 64 + qk));
    #pragma unroll
    for (int n = 0; n < 4; ++n)
      bfv1[n] = *(const bf16x8*)(bB + swz(wn * 64 + n * 16 + lr, 64 + qk));
    #pragma unroll
    for (int m = 0; m < 6; ++m)
      #pragma unroll
      for (int n = 0; n < 4; ++n)
        acc[m][n] = __builtin_amdgcn_mfma_f32_16x16x32_bf16(af0[m], bfv0[n], acc[m][n], 0, 0, 0);
    #pragma unroll
    for (int m = 0; m < 6; ++m)
      #pragma unroll
      for (int n = 0; n < 4; ++n)
        acc[m][n] = __builtin_amdgcn_mfma_f32_16x16x32_bf16(af1[m], bfv1[n], acc[m][n], 0, 0, 0);
    asm volatile("s_waitcnt lgkmcnt(0)" ::: "memory");  // "memory" blocks hoisting
    __builtin_amdgcn_s_barrier();
  }

  // keep everything live; overwritten by msg_kernel afterwards
  float* po = out + ((size_t)blockIdx.x * 512 + tid) * 96;
  int idx = 0;
  #pragma unroll
  for (int m = 0; m < 6; ++m)
    #pragma unroll
    for (int n = 0; n < 4; ++n) { *(f32x4*)(po + idx * 4) = acc[m][n]; ++idx; }
}

// ==================== MAIN: unchanged round-9 kernel ====================
__global__ __launch_bounds__(512, 2)
void msg_kernel(const float* __restrict__ h_w, const float* __restrict__ e_vw,
                const unsigned short* __restrict__ Wtile,
                const float* __restrict__ be, const float* __restrict__ bw,
                float* __restrict__ out) {
  __shared__ __align__(16) unsigned char smem[2 * 57344 + 768];
  float* bias_s = (float*)(smem + 114688);

  const int tid = threadIdx.x;
  const int p = blockIdx.x;
  const int slot = p >> 3;
  const int bb = (p & 7) * 16 + (slot >> 2);
  const int mt = slot & 3;
  const int bm0 = mt * 192;

  if (tid < 192) bias_s[tid] = be[bm0 + tid] + bw[bm0 + tid];

  const unsigned short* pA = Wtile + (size_t)(mt * 3) * 4096 + (size_t)tid * 8;
  const int rA = tid >> 3, kA = (tid & 7) * 16;
  int wAo[3];
  #pragma unroll
  for (int c = 0; c < 3; ++c) wAo[c] = swz(c * 64 + rA, kA);

  const int nq = tid & 63, kk = tid >> 6;
  const size_t xofs = (size_t)bb * DD * NCOL + (size_t)(kk * 8) * NCOL + nq * 4;
  const float* pE = e_vw + xofs;
  const float* pH = h_w + xofs;
  int wBo[4];
  #pragma unroll
  for (int j = 0; j < 4; ++j) wBo[j] = swz(4 * nq + j, kk * 16);

  u32x4 aR[3];
  f32x4 bR[8];

  auto issueA = [&](int T) {
    const unsigned short* q = pA + (size_t)T * 49152;
    aR[0] = *(const u32x4*)q;
    aR[1] = *(const u32x4*)(q + 4096);
    aR[2] = *(const u32x4*)(q + 8192);
  };
  auto issueB = [&](int T) {
    const float* q = (T < 12) ? (pE + (size_t)T * BK * NCOL)
                              : (pH + (size_t)(T - 12) * BK * NCOL);
    #pragma unroll
    for (int i = 0; i < 8; ++i) bR[i] = *(const f32x4*)(q + (size_t)i * NCOL);
  };
  auto storeA = [&](int buf) {
    unsigned char* base = smem + buf * 57344;
    #pragma unroll
    for (int c = 0; c < 3; ++c) *(u32x4*)(base + wAo[c]) = aR[c];
  };
  auto storeB = [&](int buf) {
    unsigned char* base = smem + buf * 57344 + 24576;
    #pragma unroll
    for (int j = 0; j < 4; ++j) {
      union { bf16 h8[8]; u32x4 q; } u;
      #pragma unroll
      for (int i = 0; i < 8; ++i) u.h8[i] = (bf16)bR[i][j];
      *(u32x4*)(base + wBo[j]) = u.q;
    }
  };

  const int lane = tid & 63, wid = tid >> 6;
  const int wm = wid >> 2, wn = wid & 3;
  const int lr = lane & 15, qk = (lane >> 4) * 16;
  f32x4 acc[6][4] = {};

  issueA(0); issueB(0);
  storeA(0); storeB(0);
  issueA(1); issueB(1);
  asm volatile("s_waitcnt lgkmcnt(0)" ::: "memory");
  __builtin_amdgcn_s_barrier();

  for (int t = 0; t < NIT; ++t) {
    const int c = t & 1;
    const unsigned char* bA = smem + c * 57344;
    const unsigned char* bB = bA + 24576;
    bf16x8 af0[6], bfv0[4], af1[6], bfv1[4];

    #pragma unroll
    for (int m = 0; m < 6; ++m)
      af0[m] = *(const bf16x8*)(bA + swz(wm * 96 + m * 16 + lr, qk));
    #pragma unroll
    for (int n = 0; n < 4; ++n)
      bfv0[n] = *(const bf16x8*)(bB + swz(wn * 64 + n * 16 + lr, qk));
    #pragma unroll
    for (int m = 0; m < 6; ++m)
      af1[m] = *(const bf16x8*)(bA + swz(wm * 96 + m * 16 + lr, 64 + qk));
    #pragma unroll
    for (int n = 0; n < 4; ++n)
      bfv1[n] = *(const bf16x8*)(bB + swz(wn * 64 + n * 16 + lr, 64 + qk));

    #pragma unroll
    for (int m = 0; m < 6; ++m)
      #pragma unroll
      for (int n = 0; n < 4; ++n)
        acc[m][n] = __builtin_amdgcn_mfma_f32_16x16x32_bf16(af0[m], bfv0[n], acc[m][n], 0, 0, 0);

    if (t < NIT - 1) { storeA(c ^ 1); storeB(c ^ 1); }
    if (t < NIT - 2) { issueA(t + 2); issueB(t + 2); }

    #pragma unroll
    for (int m = 0; m < 6; ++m)
      #pragma unroll
      for (int n = 0; n < 4; ++n)
        acc[m][n] = __builtin_amdgcn_mfma_f32_16x16x32_bf16(af1[m], bfv1[n], acc[m][n], 0, 0, 0);

    asm volatile("s_waitcnt lgkmcnt(0)" ::: "memory");
    __builtin_amdgcn_s_barrier();
  }

  float* po = out + (size_t)bb * DD * NCOL;
  const int g4 = (lane >> 4) * 4;
  #pragma unroll
  for (int m = 0; m < 6; ++m) {
    const int r0 = wm * 96 + m * 16 + g4;
    #pragma unroll
    for (int n = 0; n < 4; ++n) {
      const int col = wn * 64 + n * 16 + lr;
      #pragma unroll
      for (int j = 0; j < 4; ++j)
        po[(size_t)(bm0 + r0 + j) * NCOL + col] = acc[m][n][j] + bias_s[r0 + j];
    }
  }
}

extern "C" void kernel_launch(void* const* d_in, const int* in_sizes, int n_in,
                              void* d_out, int out_size, void* d_ws, size_t ws_size,
                              hipStream_t stream) {
  // inputs: 0:h_v(unused) 1:h_w 2:e_vw 3:We 4:be 5:Ww 6:bw
  const float* h_w  = (const float*)d_in[1];
  const float* e_vw = (const float*)d_in[2];
  const float* We   = (const float*)d_in[3];
  const float* be   = (const float*)d_in[4];
  const float* Ww   = (const float*)d_in[5];
  const float* bw   = (const float*)d_in[6];
  float* out = (float*)d_out;
  unsigned short* Wtile = (unsigned short*)d_ws;  // 2.36 MB

  prep_w<<<dim3(576), 256, 0, stream>>>(We, Ww, Wtile);
  probe_compute<<<dim3(512), 512, 0, stream>>>(Wtile, e_vw, out);  // ablation probe
  msg_kernel<<<dim3(512), 512, 0, stream>>>(h_w, e_vw, Wtile, be, bw, out);
}

// Round 15
// 436.524 us; speedup vs baseline: 1.3979x; 1.3979x over previous
//
#include <hip/hip_runtime.h>

// msg[b,o,n] = sum_d We[o,d]*e_vw[b,d,n] + sum_d Ww[o,d]*h_w[b,d,n] + be[o]+bw[o]
// B=128, D=768, N=256. Fused GEMM per batch: M=768, N=256, K=1536.
// Tile 192x256, BK=64, 8 waves (2m x 4n), wave tile 96x64.
// ROUND 15: fragment-linear LDS (1KB/fragment, lane-linear) -> ALL LDS
// accesses conflict-free (probe measured 640cy/step read conflicts on the
// old swizzle). A staged via global_load_lds DMA (3 instr/wave/step, no
// regs/cvt/ds_write; Wfrag is already in per-lane fragment order).
// Counted vmcnt(8) at step end keeps B prefetch in flight across barriers.

#define DD   768
#define NCOL 256
#define BM   192
#define BN   256
#define BK   64
#define NIT  24
#define ABYTES 24576
#define BUFSZ  57344   // A 24KB + B 32KB per buffer

typedef __bf16 bf16;
typedef __attribute__((ext_vector_type(8))) __bf16 bf16x8;
typedef __attribute__((ext_vector_type(4))) float f32x4;
typedef __attribute__((ext_vector_type(4))) unsigned int u32x4;

// global->LDS DMA, 16B/lane. LDS dest = wave-uniform base + lane*16 (HW).
// Address-space casts via integer round-trip (CK pattern).
__device__ __forceinline__ void dma16(const void* g, const void* lds_generic) {
  __builtin_amdgcn_global_load_lds(
      (const __attribute__((address_space(1))) unsigned int*)(unsigned long long)g,
      (__attribute__((address_space(3))) unsigned int*)(unsigned int)(unsigned long long)lds_generic,
      16, 0, 0);
}

// ---- prep: Wfrag[mt][T][f=s*12+M][lane] 16B chunks (round-10/11 verified) ----
// lane l of fragment (M,s): row = mt*192 + M*16 + (l&15),
//                           k = T*64 + s*32 + (l>>4)*8 .. +7 ; k<768 We else Ww
__global__ void prep_w(const float* __restrict__ We, const float* __restrict__ Ww,
                       unsigned short* __restrict__ Wfrag) {
  int i = blockIdx.x * blockDim.x + threadIdx.x;  // 147456 chunks
  int lane = i & 63;
  int r = i >> 6;
  int M = r % 12;  r /= 12;
  int s = r & 1;   r >>= 1;
  int T = r % 24;
  int mt = r / 24;
  int o = mt * 192 + M * 16 + (lane & 15);
  int k = T * 64 + s * 32 + (lane >> 4) * 8;
  const float* src = (k < DD) ? (We + (size_t)o * DD + k)
                              : (Ww + (size_t)o * DD + (k - DD));
  f32x4 v0 = *(const f32x4*)src;
  f32x4 v1 = *(const f32x4*)(src + 4);
  union { bf16 h8[8]; u32x4 q; } u;
  u.h8[0]=(bf16)v0[0]; u.h8[1]=(bf16)v0[1]; u.h8[2]=(bf16)v0[2]; u.h8[3]=(bf16)v0[3];
  u.h8[4]=(bf16)v1[0]; u.h8[5]=(bf16)v1[1]; u.h8[6]=(bf16)v1[2]; u.h8[7]=(bf16)v1[3];
  *(u32x4*)(Wfrag + (size_t)i * 8) = u.q;
}

__global__ __launch_bounds__(512, 2)
void msg_kernel(const float* __restrict__ h_w, const float* __restrict__ e_vw,
                const unsigned short* __restrict__ Wfrag,
                const float* __restrict__ be, const float* __restrict__ bw,
                float* __restrict__ out) {
  // [buf0: A 24KB | B 32KB][buf1: A | B][bias 768B]
  __shared__ __align__(16) unsigned char smem[2 * BUFSZ + 768];
  float* bias_s = (float*)(smem + 2 * BUFSZ);

  const int tid = threadIdx.x;
  // XCD map: 4 m-blocks of a batch on one XCD (rounds 5-13).
  const int p = blockIdx.x;
  const int slot = p >> 3;
  const int bb = (p & 7) * 16 + (slot >> 2);
  const int mt = slot & 3;
  const int bm0 = mt * 192;

  if (tid < 192) bias_s[tid] = be[bm0 + tid] + bw[bm0 + tid];

  const int lane = tid & 63, wid = tid >> 6;
  const int wm = wid >> 2, wn = wid & 3;
  const int wm6 = wm * 6;

  // ---- A DMA: wave wid covers fragments f = wid*3 + jj, jj=0..2 ----
  const unsigned short* pWt = Wfrag + (size_t)(mt * 24) * 24 * 64 * 8;
  auto dmaA = [&](int buf, int T) {
    const unsigned short* tb = pWt + (size_t)T * 24 * 64 * 8;
    #pragma unroll
    for (int jj = 0; jj < 3; ++jj) {
      const int f = wid * 3 + jj;
      dma16(tb + (size_t)(f * 64 + lane) * 8, smem + buf * BUFSZ + f * 1024);
    }
  };

  // ---- B staging: thread (nq=tid&63 -> cols 4nq..+3, kk=tid>>6 -> k kk*8..+7)
  const int nq = tid & 63, kk = tid >> 6;
  const int sB = kk >> 2, kc = kk & 3, nb4 = nq >> 2, nl = nq & 3;
  const size_t xofs = (size_t)bb * DD * NCOL + (size_t)(kk * 8) * NCOL + nq * 4;
  const float* pE = e_vw + xofs;
  const float* pH = h_w + xofs;
  const int cbase = (sB * 16 + nb4) * 64 + kc * 16 + nl * 4;  // chunk idx (+j)

  f32x4 bR[8];   // B prefetch (fp32, 4 cols x 8 k)

  auto issueB = [&](int T) {
    const float* q = (T < 12) ? (pE + (size_t)T * BK * NCOL)
                              : (pH + (size_t)(T - 12) * BK * NCOL);
    #pragma unroll
    for (int i = 0; i < 8; ++i) bR[i] = *(const f32x4*)(q + (size_t)i * NCOL);
  };
  // fragment-linear B writes, rotated j -> uniform 8 lanes/16B-slot (no conflict)
  auto storeB = [&](int buf) {
    unsigned char* base = smem + buf * BUFSZ + ABYTES;
    #pragma unroll
    for (int i = 0; i < 4; ++i) {
      const int j = (i + nb4) & 3;
      union { bf16 h8[8]; u32x4 q; } u;
      #pragma unroll
      for (int r = 0; r < 8; ++r) u.h8[r] = (bf16)bR[r][j];
      *(u32x4*)(base + (size_t)(cbase + j) * 16) = u.q;
    }
  };

  f32x4 acc[6][4] = {};

  // ---- prologue: B(0) loads, A(0) DMA, stage B(0), prefetch B(1) ----
  issueB(0);
  dmaA(0, 0);
  __builtin_amdgcn_sched_barrier(0);
  storeB(0);                 // compiler-counted vmcnt retires B(0), DMAs fly
  issueB(1);
  asm volatile("s_waitcnt vmcnt(8) lgkmcnt(0)" ::: "memory");  // retire DMA(0)
  __builtin_amdgcn_s_barrier();

  // ---- main loop ----
  for (int t = 0; t < NIT; ++t) {
    const int c = t & 1;
    const unsigned char* bA = smem + c * BUFSZ;
    const unsigned char* bB = bA + ABYTES;

    // A DMA for t+1 at step top: full-step latency cover, oldest in vmcnt
    if (t < NIT - 1) dmaA(c ^ 1, t + 1);
    __builtin_amdgcn_sched_barrier(0);

    bf16x8 af0[6], bfv0[4], af1[6], bfv1[4];
    // slice-0 fragments: linear 1KB reads, conflict-free
    #pragma unroll
    for (int m = 0; m < 6; ++m)
      af0[m] = *(const bf16x8*)(bA + (size_t)((wm6 + m) * 64 + lane) * 16);
    #pragma unroll
    for (int n = 0; n < 4; ++n)
      bfv0[n] = *(const bf16x8*)(bB + (size_t)((wn * 4 + n) * 64 + lane) * 16);

    // MFMA cluster 0 (gated on counted lgkm of 10 linear reads only)
    #pragma unroll
    for (int m = 0; m < 6; ++m)
      #pragma unroll
      for (int n = 0; n < 4; ++n)
        acc[m][n] = __builtin_amdgcn_mfma_f32_16x16x32_bf16(af0[m], bfv0[n], acc[m][n], 0, 0, 0);

    // slice-1 fragments
    #pragma unroll
    for (int m = 0; m < 6; ++m)
      af1[m] = *(const bf16x8*)(bA + (size_t)((12 + wm6 + m) * 64 + lane) * 16);
    #pragma unroll
    for (int n = 0; n < 4; ++n)
      bfv1[n] = *(const bf16x8*)(bB + (size_t)((16 + wn * 4 + n) * 64 + lane) * 16);

    // stage B(t+1) (consumes bR; its loads are ~1 step old), then refill
    if (t < NIT - 1) storeB(c ^ 1);
    if (t < NIT - 2) issueB(t + 2);

    // MFMA cluster 1
    #pragma unroll
    for (int m = 0; m < 6; ++m)
      #pragma unroll
      for (int n = 0; n < 4; ++n)
        acc[m][n] = __builtin_amdgcn_mfma_f32_16x16x32_bf16(af1[m], bfv1[n], acc[m][n], 0, 0, 0);

    // step end: retire this step's 3 DMAs (oldest), keep 8 B loads in flight;
    // lgkm(0) = dbuf read/write visibility.
    if (t < NIT - 2) {
      asm volatile("s_waitcnt vmcnt(8) lgkmcnt(0)" ::: "memory");
    } else {
      asm volatile("s_waitcnt vmcnt(0) lgkmcnt(0)" ::: "memory");
    }
    __builtin_amdgcn_s_barrier();
  }

  // ---- epilogue: bias + store. C/D: col=lane&15, row=(lane>>4)*4+reg ----
  float* po = out + (size_t)bb * DD * NCOL;
  const int lr = lane & 15;
  const int g4 = (lane >> 4) * 4;
  #pragma unroll
  for (int m = 0; m < 6; ++m) {
    const int r0 = wm * 96 + m * 16 + g4;
    #pragma unroll
    for (int n = 0; n < 4; ++n) {
      const int col = wn * 64 + n * 16 + lr;
      #pragma unroll
      for (int j = 0; j < 4; ++j)
        po[(size_t)(bm0 + r0 + j) * NCOL + col] = acc[m][n][j] + bias_s[r0 + j];
    }
  }
}

extern "C" void kernel_launch(void* const* d_in, const int* in_sizes, int n_in,
                              void* d_out, int out_size, void* d_ws, size_t ws_size,
                              hipStream_t stream) {
  // inputs: 0:h_v(unused) 1:h_w 2:e_vw 3:We 4:be 5:Ww 6:bw
  const float* h_w  = (const float*)d_in[1];
  const float* e_vw = (const float*)d_in[2];
  const float* We   = (const float*)d_in[3];
  const float* be   = (const float*)d_in[4];
  const float* Ww   = (const float*)d_in[5];
  const float* bw   = (const float*)d_in[6];
  float* out = (float*)d_out;
  unsigned short* Wfrag = (unsigned short*)d_ws;  // 147456 x 16B = 2.36 MB

  prep_w<<<dim3(576), 256, 0, stream>>>(We, Ww, Wfrag);
  msg_kernel<<<dim3(512), 512, 0, stream>>>(h_w, e_vw, Wfrag, be, bw, out);
}